// Round 14
// baseline (351.836 us; speedup 1.0000x reference)
//
#include <hip/hip_runtime.h>
#include <hip/hip_bf16.h>

#define BB 8
#define NN 256
#define DD 128
#define HH 512
#define EPSV 1e-5f

typedef unsigned short ushort_t;
typedef __attribute__((ext_vector_type(8))) short bf16x8;
typedef __attribute__((ext_vector_type(4))) float f32x4;

#if defined(__has_builtin)
#if __has_builtin(__builtin_amdgcn_sched_barrier)
#define SCHED_FENCE() __builtin_amdgcn_sched_barrier(0)
#endif
#endif
#ifndef SCHED_FENCE
#define SCHED_FENCE()
#endif

__device__ __forceinline__ ushort_t f2b(float v){
  __hip_bfloat16 h = __float2bfloat16(v);
  return *(ushort_t*)&h;
}

__device__ __forceinline__ void waveRed2(float &a, float &b){
  #pragma unroll
  for (int off=32; off>=1; off>>=1){
    a += __shfl_xor(a, off, 64);
    b += __shfl_xor(b, off, 64);
  }
}

__device__ __forceinline__ void poolMerge(float &m1, float &m2, int &am,
                                          float o1, float o2, int oa){
  if (o1 > m1){ m2 = fmaxf(m1, o2); m1 = o1; am = oa; }
  else        { m2 = fmaxf(m2, o1); }
}

// SINGLE kernel, 256 blocks x 512 threads, zero inter-block communication.
// Each block: closed-form embed stats -> embed pool (in-block, whole batch)
// -> layer-0 for ALL 256 batch tokens (16 tiles of 16 through the MFMA
// pipeline; redundant across the batch's 32 blocks but removes the only
// cross-block dependency) accumulating layer-1 pool stats in registers
// -> layer-1 for own 8 tokens -> final write to d_out.
__global__ __launch_bounds__(512, 2) void k_all(
    const float* __restrict__ x, const float* __restrict__ We,
    const float* __restrict__ be, const float* __restrict__ ge,
    const float* __restrict__ bge,
    const float* __restrict__ Wp0, const float* __restrict__ bp0,
    const float* __restrict__ gp0, const float* __restrict__ bgp0,
    const float* __restrict__ W10, const float* __restrict__ b10,
    const float* __restrict__ W20, const float* __restrict__ b20,
    const float* __restrict__ gf0, const float* __restrict__ bgf0,
    const float* __restrict__ Wp1, const float* __restrict__ bp1,
    const float* __restrict__ gp1, const float* __restrict__ bgp1,
    const float* __restrict__ W11, const float* __restrict__ b11,
    const float* __restrict__ W21, const float* __restrict__ b21,
    const float* __restrict__ gf1, const float* __restrict__ bgf1,
    float* __restrict__ hio)
{
  int tid = threadIdx.x;
  int d = tid & 127, fourth = tid >> 7;
  int wv = tid >> 6;
  int lane = tid & 63;
  int m = lane & 15, q = lane >> 4;
  int t0 = blockIdx.x * 8;
  int b = blockIdx.x >> 5;
  int nown = t0 & 255;

  __shared__ float    xs[512];         // 2K   batch x
  __shared__ float    red9[2][12];
  __shared__ float    stats[12];
  __shared__ float    hres[16*128];    // 8K   embed-h / h0 per tile
  __shared__ ushort_t catb[16*256];    // 8K
  __shared__ float    sA[16*128];      // 8K
  __shared__ ushort_t h1b[16*128];     // 4K
  __shared__ float    h1f[16*128];     // 8K
  __shared__ ushort_t ub[16*512];      // 16K
  __shared__ float    hown[8*128];     // 4K   own tokens' h0
  __shared__ float fm1[128], fm2[128];
  __shared__ int   fam[128];
  __shared__ float sm1[4][128], sm2[4][128];
  __shared__ int   sam[4][128];

  int n0a = wv*16;

  // ======== layer-0 A/B weight frags: batched f32 loads, pinned early ====
  float wAf[8][8];
  #pragma unroll
  for (int ks=0; ks<8; ++ks)
    #pragma unroll
    for (int j=0; j<8; ++j)
      wAf[ks][j] = Wp0[(size_t)(ks*32 + q*8 + j)*128 + n0a + m];
  float wBf[16][8];
  #pragma unroll
  for (int i=0;i<4;++i){
    int n0 = i*128 + wv*16;
    #pragma unroll
    for (int ks=0; ks<4; ++ks)
      #pragma unroll
      for (int j=0;j<8;++j)
        wBf[i*4+ks][j] = W10[(size_t)(ks*32 + q*8 + j)*512 + n0 + m];
  }
  SCHED_FENCE();

  // ======== prologue: xs, embed closed-form stats, embed pool ============
  xs[tid] = x[(size_t)b*512 + tid];
  {
    float a = We[d], bw = We[128+d], c = be[d];
    if (fourth == 0){
      float r0=a, r1=bw;        waveRed2(r0,r1);
      float r2=c, r3=a*a;       waveRed2(r2,r3);
      float r4=bw*bw, r5=c*c;   waveRed2(r4,r5);
      float r6=a*bw, r7=a*c;    waveRed2(r6,r7);
      float r8=bw*c, r9=0.f;    waveRed2(r8,r9);
      int w = (tid >> 6) & 1;
      if (lane == 0){
        red9[w][0]=r0; red9[w][1]=r1; red9[w][2]=r2; red9[w][3]=r3;
        red9[w][4]=r4; red9[w][5]=r5; red9[w][6]=r6; red9[w][7]=r7;
        red9[w][8]=r8;
      }
    }
    __syncthreads();
    if (tid < 9) stats[tid] = (red9[0][tid] + red9[1][tid]) * (1.f/128);
    __syncthreads();
    float mA=stats[0], mB=stats[1], mC=stats[2];
    float SAA=stats[3], SBB=stats[4], SCC=stats[5];
    float SAB=stats[6], SAC=stats[7], SBC=stats[8];
    float gev = ge[d], bgev = bge[d];
    float m1=-3.4e38f, m2=-3.4e38f; int am=0;
    for (int i=0;i<64;++i){
      int n = fourth*64 + i;
      float x0 = xs[2*n], x1 = xs[2*n+1];
      float v    = fmaf(x0, a,  fmaf(x1, bw, c));
      float mean = fmaf(x0, mA, fmaf(x1, mB, mC));
      float ev2  = x0*x0*SAA + x1*x1*SBB + SCC
                 + 2.f*(x0*x1*SAB + x0*SAC + x1*SBC);
      float var = ev2 - mean*mean;
      float hv = (v-mean)*rsqrtf(var+EPSV)*gev + bgev;
      poolMerge(m1,m2,am, hv, -3.4e38f, n);
    }
    sm1[fourth][d]=m1; sm2[fourth][d]=m2; sam[fourth][d]=am;
  }
  __syncthreads();
  if (fourth==0){
    float m1=sm1[0][d], m2=sm2[0][d]; int am=sam[0][d];
    #pragma unroll
    for (int p=1;p<4;++p) poolMerge(m1,m2,am, sm1[p][d], sm2[p][d], sam[p][d]);
    fm1[d]=m1; fm2[d]=m2; fam[d]=am;
  }
  SCHED_FENCE();
  // ---- convert layer-0 A/B frags to bf16 registers ----
  bf16x8 wfA[8];
  #pragma unroll
  for (int ks=0; ks<8; ++ks)
    #pragma unroll
    for (int j=0;j<8;++j) wfA[ks][j] = (short)f2b(wAf[ks][j]);
  bf16x8 wfB[16];
  #pragma unroll
  for (int kk=0; kk<16; ++kk)
    #pragma unroll
    for (int j=0;j<8;++j) wfB[kk][j] = (short)f2b(wBf[kk][j]);
  __syncthreads();

  // ======== batch loop: layer-0 for all 256 tokens, 16 tiles of 16 =======
  float r_m1 = -3.4e38f, r_m2 = -3.4e38f; int r_am = 0;   // layer-1 pool
  float mA=stats[0], mB=stats[1], mC=stats[2];
  float SAA=stats[3], SBB=stats[4], SCC=stats[5];
  float SAB=stats[6], SAC=stats[7], SBC=stats[8];

  for (int tile=0; tile<16; ++tile){
    int nbase = tile*16;
    // ---- embed-h for this tile (closed form) + cat build ----
    {
      float gev = ge[d], bgev = bge[d];
      #pragma unroll
      for (int rep=0; rep<4; ++rep){
        int t = rep*4 + fourth;
        int n = nbase + t;
        float x0 = xs[2*n], x1 = xs[2*n+1];
        float v    = fmaf(x0, We[d],  fmaf(x1, We[128+d], be[d]));
        float mean = fmaf(x0, mA, fmaf(x1, mB, mC));
        float ev2  = x0*x0*SAA + x1*x1*SBB + SCC
                   + 2.f*(x0*x1*SAB + x0*SAC + x1*SBC);
        float var = ev2 - mean*mean;
        float hv = (v-mean)*rsqrtf(var+EPSV)*gev + bgev;
        hres[t*128 + d] = hv;
        catb[t*256 + d] = f2b(hv);
        float pv = (n == fam[d]) ? fm2[d] : fm1[d];
        catb[t*256 + 128 + d] = f2b(pv);
      }
    }
    __syncthreads();

    // ---- stage A ----
    {
      f32x4 acc = {0.f,0.f,0.f,0.f};
      const ushort_t* ap = catb + m*256 + q*8;
      #pragma unroll
      for (int ks=0; ks<8; ++ks){
        bf16x8 af = *(const bf16x8*)(ap + ks*32);
        acc = __builtin_amdgcn_mfma_f32_16x16x32_bf16(af, wfA[ks], acc, 0,0,0);
      }
      #pragma unroll
      for (int r=0;r<4;++r) sA[(q*4+r)*128 + n0a + m] = acc[r];
    }
    __syncthreads();

    // ---- LN-A: wave handles tokens wv and wv+8 ----
    #pragma unroll
    for (int half=0; half<2; ++half){
      int t = wv + half*8, g = lane;
      float2 v2 = *(const float2*)&sA[t*128 + 2*g];
      float v0 = v2.x + bp0[2*g]   + hres[t*128 + 2*g];
      float v1 = v2.y + bp0[2*g+1] + hres[t*128 + 2*g + 1];
      float s = v0+v1, qq = v0*v0 + v1*v1;
      waveRed2(s,qq);
      float mean = s*(1.f/128), var = qq*(1.f/128) - mean*mean;
      float rs = rsqrtf(var + EPSV);
      float o0 = (v0-mean)*rs*gp0[2*g]   + bgp0[2*g];
      float o1 = (v1-mean)*rs*gp0[2*g+1] + bgp0[2*g+1];
      unsigned pk = (unsigned)f2b(o0) | ((unsigned)f2b(o1) << 16);
      *(unsigned*)&h1b[t*128 + 2*g] = pk;
      *(float2*)&h1f[t*128 + 2*g] = make_float2(o0, o1);
    }
    __syncthreads();

    // ---- stage B ----
    {
      const ushort_t* ap = h1b + m*128 + q*8;
      bf16x8 af[4];
      #pragma unroll
      for (int ks=0; ks<4; ++ks) af[ks] = *(const bf16x8*)(ap + ks*32);
      #pragma unroll
      for (int i=0;i<4;++i){
        int n0 = i*128 + wv*16;
        f32x4 acc = {0.f,0.f,0.f,0.f};
        #pragma unroll
        for (int ks=0; ks<4; ++ks)
          acc = __builtin_amdgcn_mfma_f32_16x16x32_bf16(af[ks], wfB[i*4+ks], acc, 0,0,0);
        float bb = b10[n0+m];
        #pragma unroll
        for (int r=0;r<4;++r)
          ub[(q*4+r)*512 + n0 + m] = f2b(fmaxf(acc[r] + bb, 0.f));
      }
    }
    __syncthreads();

    // ---- stage C: inline gathers (L2-warm after tile 0), 2 halves ----
    {
      f32x4 acc = {0.f,0.f,0.f,0.f};
      const ushort_t* ap = ub + m*512 + q*8;
      #pragma unroll
      for (int half=0; half<2; ++half){
        float wC[8][8];
        #pragma unroll
        for (int ks=0; ks<8; ++ks)
          #pragma unroll
          for (int j=0;j<8;++j)
            wC[ks][j] = W20[(size_t)((half*8+ks)*32 + q*8 + j)*128 + n0a + m];
        SCHED_FENCE();
        #pragma unroll
        for (int ks=0; ks<8; ++ks){
          bf16x8 wf;
          #pragma unroll
          for (int j=0;j<8;++j) wf[j] = (short)f2b(wC[ks][j]);
          bf16x8 af = *(const bf16x8*)(ap + (half*8+ks)*32);
          acc = __builtin_amdgcn_mfma_f32_16x16x32_bf16(af, wf, acc, 0,0,0);
        }
      }
      #pragma unroll
      for (int r=0;r<4;++r) sA[(q*4+r)*128 + n0a + m] = acc[r];
    }
    __syncthreads();

    // ---- LN-C -> h0 in hres ----
    #pragma unroll
    for (int half=0; half<2; ++half){
      int t = wv + half*8, g = lane;
      float2 v2 = *(const float2*)&sA[t*128 + 2*g];
      float v0 = v2.x + b20[2*g]   + h1f[t*128 + 2*g];
      float v1 = v2.y + b20[2*g+1] + h1f[t*128 + 2*g + 1];
      float s = v0+v1, qq = v0*v0 + v1*v1;
      waveRed2(s,qq);
      float mean = s*(1.f/128), var = qq*(1.f/128) - mean*mean;
      float rs = rsqrtf(var + EPSV);
      float o0 = (v0-mean)*rs*gf0[2*g]   + bgf0[2*g];
      float o1 = (v1-mean)*rs*gf0[2*g+1] + bgf0[2*g+1];
      *(float2*)&hres[t*128 + 2*g] = make_float2(o0, o1);
    }
    __syncthreads();

    // ---- accumulate layer-1 pool stats; stash own tokens' h0 ----
    if (tid < 128){
      #pragma unroll
      for (int p=0;p<16;++p)
        poolMerge(r_m1, r_m2, r_am, hres[p*128 + tid], -3.4e38f, nbase + p);
    }
    if (tile == (nown >> 4)){
      int r0 = nown & 15;
      #pragma unroll
      for (int rep=0; rep<2; ++rep){
        int t = fourth*2 + rep;
        hown[t*128 + d] = hres[(r0 + t)*128 + d];
      }
    }
    __syncthreads();
  }

  // ======== layer 1 for own 8 tokens ========
  if (tid < 128){ fm1[tid] = r_m1; fm2[tid] = r_m2; fam[tid] = r_am; }
  __syncthreads();

  // ---- cat build: 4 reps -> rows 0..7 all written (R13 bug: rep<2) ----
  #pragma unroll
  for (int rep=0; rep<4; ++rep){
    int e = rep*512 + tid;
    int t = e >> 8, cc = e & 255;
    int n = nown + t;
    float v;
    if (cc < DD) v = hown[t*128 + cc];
    else { int c2 = cc - DD; v = (n==fam[c2]) ? fm2[c2] : fm1[c2]; }
    catb[t*256 + cc] = f2b(v);
  }
  __syncthreads();

  // ---- stage A ----
  {
    float wA[8][8];
    #pragma unroll
    for (int ks=0; ks<8; ++ks)
      #pragma unroll
      for (int j=0; j<8; ++j)
        wA[ks][j] = Wp1[(size_t)(ks*32 + q*8 + j)*128 + n0a + m];
    SCHED_FENCE();
    f32x4 acc = {0.f,0.f,0.f,0.f};
    const ushort_t* ap = catb + m*256 + q*8;
    #pragma unroll
    for (int ks=0; ks<8; ++ks){
      bf16x8 wf;
      #pragma unroll
      for (int j=0;j<8;++j) wf[j] = (short)f2b(wA[ks][j]);
      bf16x8 af = *(const bf16x8*)(ap + ks*32);
      acc = __builtin_amdgcn_mfma_f32_16x16x32_bf16(af, wf, acc, 0,0,0);
    }
    #pragma unroll
    for (int r=0;r<4;++r) sA[(q*4+r)*128 + n0a + m] = acc[r];
  }
  __syncthreads();

  // ---- LN-A (8 tokens) ----
  {
    int t = wv, g = lane;
    float2 v2 = *(const float2*)&sA[t*128 + 2*g];
    float v0 = v2.x + bp1[2*g]   + hown[t*128 + 2*g];
    float v1 = v2.y + bp1[2*g+1] + hown[t*128 + 2*g + 1];
    float s = v0+v1, qq = v0*v0 + v1*v1;
    waveRed2(s,qq);
    float mean = s*(1.f/128), var = qq*(1.f/128) - mean*mean;
    float rs = rsqrtf(var + EPSV);
    float o0 = (v0-mean)*rs*gp1[2*g]   + bgp1[2*g];
    float o1 = (v1-mean)*rs*gp1[2*g+1] + bgp1[2*g+1];
    unsigned pk = (unsigned)f2b(o0) | ((unsigned)f2b(o1) << 16);
    *(unsigned*)&h1b[t*128 + 2*g] = pk;
    *(float2*)&h1f[t*128 + 2*g] = make_float2(o0, o1);
  }
  __syncthreads();

  // ---- stage B ----
  {
    const ushort_t* ap = h1b + m*128 + q*8;
    bf16x8 af[4];
    #pragma unroll
    for (int ks=0; ks<4; ++ks) af[ks] = *(const bf16x8*)(ap + ks*32);
    #pragma unroll
    for (int half=0; half<2; ++half){
      float wB[8][8];
      #pragma unroll
      for (int i=0;i<2;++i){
        int n0 = (half*2+i)*128 + wv*16;
        #pragma unroll
        for (int ks=0; ks<4; ++ks)
          #pragma unroll
          for (int j=0;j<8;++j)
            wB[i*4+ks][j] = W11[(size_t)(ks*32 + q*8 + j)*512 + n0 + m];
      }
      SCHED_FENCE();
      #pragma unroll
      for (int i=0;i<2;++i){
        int n0 = (half*2+i)*128 + wv*16;
        f32x4 acc = {0.f,0.f,0.f,0.f};
        #pragma unroll
        for (int ks=0; ks<4; ++ks){
          bf16x8 wf;
          #pragma unroll
          for (int j=0;j<8;++j) wf[j] = (short)f2b(wB[i*4+ks][j]);
          acc = __builtin_amdgcn_mfma_f32_16x16x32_bf16(af[ks], wf, acc, 0,0,0);
        }
        float bb = b11[n0+m];
        #pragma unroll
        for (int r=0;r<4;++r)
          ub[(q*4+r)*512 + n0 + m] = f2b(fmaxf(acc[r] + bb, 0.f));
      }
    }
  }
  __syncthreads();

  // ---- stage C ----
  {
    f32x4 acc = {0.f,0.f,0.f,0.f};
    const ushort_t* ap = ub + m*512 + q*8;
    #pragma unroll
    for (int half=0; half<2; ++half){
      float wC[8][8];
      #pragma unroll
      for (int ks=0; ks<8; ++ks)
        #pragma unroll
        for (int j=0;j<8;++j)
          wC[ks][j] = W21[(size_t)((half*8+ks)*32 + q*8 + j)*128 + n0a + m];
      SCHED_FENCE();
      #pragma unroll
      for (int ks=0; ks<8; ++ks){
        bf16x8 wf;
        #pragma unroll
        for (int j=0;j<8;++j) wf[j] = (short)f2b(wC[ks][j]);
        bf16x8 af = *(const bf16x8*)(ap + (half*8+ks)*32);
        acc = __builtin_amdgcn_mfma_f32_16x16x32_bf16(af, wf, acc, 0,0,0);
      }
    }
    #pragma unroll
    for (int r=0;r<4;++r) sA[(q*4+r)*128 + n0a + m] = acc[r];
  }
  __syncthreads();

  // ---- LN-C -> final output ----
  {
    int t = wv, g = lane;
    float2 v2 = *(const float2*)&sA[t*128 + 2*g];
    float v0 = v2.x + b21[2*g]   + h1f[t*128 + 2*g];
    float v1 = v2.y + b21[2*g+1] + h1f[t*128 + 2*g + 1];
    float s = v0+v1, qq = v0*v0 + v1*v1;
    waveRed2(s,qq);
    float mean = s*(1.f/128), var = qq*(1.f/128) - mean*mean;
    float rs = rsqrtf(var + EPSV);
    float o0 = (v0-mean)*rs*gf1[2*g]   + bgf1[2*g];
    float o1 = (v1-mean)*rs*gf1[2*g+1] + bgf1[2*g+1];
    *(float2*)&hio[(size_t)(t0+t)*DD + 2*g] = make_float2(o0, o1);
  }
}

extern "C" void kernel_launch(void* const* d_in, const int* in_sizes, int n_in,
                              void* d_out, int out_size, void* d_ws, size_t ws_size,
                              hipStream_t stream)
{
  const float* x   = (const float*)d_in[0];
  const float* We  = (const float*)d_in[1];
  const float* be  = (const float*)d_in[2];
  const float* ge  = (const float*)d_in[3];
  const float* bge = (const float*)d_in[4];
  const float* Wp  = (const float*)d_in[5];
  const float* bp  = (const float*)d_in[6];
  const float* gp  = (const float*)d_in[7];
  const float* bgp = (const float*)d_in[8];
  const float* W1  = (const float*)d_in[9];
  const float* b1  = (const float*)d_in[10];
  const float* W2  = (const float*)d_in[11];
  const float* b2  = (const float*)d_in[12];
  const float* gf  = (const float*)d_in[13];
  const float* bgf = (const float*)d_in[14];
  float* hio = (float*)d_out;

  k_all<<<(BB*NN)/8, 512, 0, stream>>>(x, We, be, ge, bge,
      Wp,                    bp,       gp,       bgp,
      W1,                    b1,       W2,       b2,
      gf,                    bgf,
      Wp + (size_t)2*DD*DD,  bp + DD,  gp + DD,  bgp + DD,
      W1 + (size_t)DD*HH,    b1 + HH,  W2 + (size_t)HH*DD, b2 + DD,
      gf + DD,               bgf + DD,
      hio);
}

// Round 15
// 115.245 us; speedup vs baseline: 3.0529x; 3.0529x over previous
//
#include <hip/hip_runtime.h>
#include <hip/hip_bf16.h>

#define BB 8
#define NN 256
#define DD 128
#define HH 512
#define LL 2
#define EPSV 1e-5f
#define TPB 8            // tokens per block
#define BPL (NN/TPB)     // pool partials per batch = 32

typedef unsigned short ushort_t;
typedef __attribute__((ext_vector_type(8))) short bf16x8;
typedef __attribute__((ext_vector_type(4))) float f32x4;

#if defined(__has_builtin)
#if __has_builtin(__builtin_amdgcn_sched_barrier)
#define SCHED_FENCE() __builtin_amdgcn_sched_barrier(0)
#endif
#endif
#ifndef SCHED_FENCE
#define SCHED_FENCE()
#endif

__device__ __forceinline__ ushort_t f2b(float v){
  __hip_bfloat16 h = __float2bfloat16(v);
  return *(ushort_t*)&h;
}

__device__ __forceinline__ void waveRed2(float &a, float &b){
  #pragma unroll
  for (int off=32; off>=1; off>>=1){
    a += __shfl_xor(a, off, 64);
    b += __shfl_xor(b, off, 64);
  }
}

__device__ __forceinline__ void poolMerge(float &m1, float &m2, int &am,
                                          float o1, float o2, int oa){
  if (o1 > m1){ m2 = fmaxf(m1, o2); m1 = o1; am = oa; }
  else        { m2 = fmaxf(m2, o1); }
}

// One kernel per layer, 256 blocks x 512 threads, plain launches.
// layer==0: closed-form embed (LN stats are affine in x -> 9 scalars of
//   We/be), full-batch pool scan IN-BLOCK (no cross-block dependency),
//   then layer-0 GEMMs; writes h0 to hio and layer-1 pool partials.
// layer==1: merges the 32 global pool partials, reads own h0 from hio,
//   layer-1 GEMMs, writes final h to hio (== d_out).
// Weights are consumed directly from f32 [K][N]: each wave gathers its
// B-fragments (8 scalar dwords each), batch-issued + sched-fenced, then
// converted to bf16 in registers.
__global__ __launch_bounds__(512, 2) void k_net(
    int layer,
    const float* __restrict__ x, const float* __restrict__ We,
    const float* __restrict__ be, const float* __restrict__ ge,
    const float* __restrict__ bge,
    float* __restrict__ hio,
    float* __restrict__ pm1, float* __restrict__ pm2, int* __restrict__ pma,
    const float* __restrict__ Wp, const float* __restrict__ bp,
    const float* __restrict__ gp, const float* __restrict__ bgp,
    const float* __restrict__ W1, const float* __restrict__ b1,
    const float* __restrict__ W2, const float* __restrict__ b2,
    const float* __restrict__ gf, const float* __restrict__ bgf)
{
  int tid = threadIdx.x;
  int d = tid & 127, fourth = tid >> 7;
  int wv = tid >> 6;            // wave 0..7
  int lane = tid & 63;
  int m = lane & 15, q = lane >> 4;
  int t0 = blockIdx.x * TPB;
  int b = t0 >> 8;
  int blk = (t0 >> 3) & (BPL-1);

  __shared__ float    hcur[8*128];    // 4K  h input for own 8 tokens
  __shared__ ushort_t catb[16*256];   // 8K  bf16 A-operand, stage A
  __shared__ float    sA[16*128];     // 8K  f32 GEMM out (A, then C)
  __shared__ ushort_t h1b[16*128];    // 4K  bf16 A-operand, stage B
  __shared__ float    h1f[8*128];     // 4K  f32 h1 (stage-C residual)
  __shared__ ushort_t ub[16*512];     // 16K bf16 A-operand, stage C
  __shared__ float fm1[128], fm2[128];
  __shared__ int   fam[128];
  __shared__ float sm1[4][128], sm2[4][128];
  __shared__ int   sam[4][128];
  __shared__ float xs[512];
  __shared__ float red9[2][12];
  __shared__ float stats[12];

  if (layer == 0){
    // ---- stage x for the whole batch (256 tokens x 2) ----
    xs[tid] = x[(size_t)b*512 + tid];
    // ---- 9 reduction scalars of (We,be) over d ----
    float a = We[d], bw = We[128+d], c = be[d];
    if (fourth == 0){
      float r0=a, r1=bw;        waveRed2(r0,r1);
      float r2=c, r3=a*a;       waveRed2(r2,r3);
      float r4=bw*bw, r5=c*c;   waveRed2(r4,r5);
      float r6=a*bw, r7=a*c;    waveRed2(r6,r7);
      float r8=bw*c, r9=0.f;    waveRed2(r8,r9);
      int w = (tid >> 6) & 1;
      if (lane == 0){
        red9[w][0]=r0; red9[w][1]=r1; red9[w][2]=r2; red9[w][3]=r3;
        red9[w][4]=r4; red9[w][5]=r5; red9[w][6]=r6; red9[w][7]=r7;
        red9[w][8]=r8;
      }
    }
    __syncthreads();
    if (tid < 9) stats[tid] = (red9[0][tid] + red9[1][tid]) * (1.f/128);
    __syncthreads();
    float mA=stats[0], mB=stats[1], mC=stats[2];
    float SAA=stats[3], SBB=stats[4], SCC=stats[5];
    float SAB=stats[6], SAC=stats[7], SBC=stats[8];
    float gev = ge[d], bgev = bge[d];
    // ---- full-batch pool scan: fourth f covers tokens f*64..f*64+63 ----
    float m1=-3.4e38f, m2=-3.4e38f; int am=0;
    for (int i=0;i<64;++i){
      int n = fourth*64 + i;
      float x0 = xs[2*n], x1 = xs[2*n+1];
      float v    = fmaf(x0, a,  fmaf(x1, bw, c));
      float mean = fmaf(x0, mA, fmaf(x1, mB, mC));
      float ev2  = x0*x0*SAA + x1*x1*SBB + SCC
                 + 2.f*(x0*x1*SAB + x0*SAC + x1*SBC);
      float var = ev2 - mean*mean;
      float hv = (v-mean)*rsqrtf(var+EPSV)*gev + bgev;
      poolMerge(m1,m2,am, hv, -3.4e38f, n);
    }
    sm1[fourth][d]=m1; sm2[fourth][d]=m2; sam[fourth][d]=am;
    // ---- own 8 tokens' h ----
    #pragma unroll
    for (int rep=0; rep<2; ++rep){
      int t = fourth*2 + rep;
      int n = (t0 & 255) + t;
      float x0 = xs[2*n], x1 = xs[2*n+1];
      float v    = fmaf(x0, a,  fmaf(x1, bw, c));
      float mean = fmaf(x0, mA, fmaf(x1, mB, mC));
      float ev2  = x0*x0*SAA + x1*x1*SBB + SCC
                 + 2.f*(x0*x1*SAB + x0*SAC + x1*SBC);
      float var = ev2 - mean*mean;
      hcur[t*128 + d] = (v-mean)*rsqrtf(var+EPSV)*gev + bgev;
    }
    __syncthreads();
  } else {
    // ---- merge the batch's 32 layer-0 pool partials (8 per fourth) ----
    {
      size_t base = ((size_t)b*BPL + fourth*8)*128 + d;
      float m1 = pm1[base], m2 = pm2[base]; int am = pma[base];
      #pragma unroll
      for (int i=1;i<8;++i)
        poolMerge(m1,m2,am, pm1[base+(size_t)i*128], pm2[base+(size_t)i*128],
                  pma[base+(size_t)i*128]);
      sm1[fourth][d]=m1; sm2[fourth][d]=m2; sam[fourth][d]=am;
    }
    // ---- own 8 tokens' h0 from hio ----
    #pragma unroll
    for (int rep=0; rep<2; ++rep){
      int t = fourth*2 + rep;
      hcur[t*128 + d] = hio[(size_t)(t0+t)*DD + d];
    }
    __syncthreads();
  }

  if (fourth==0){
    float m1=sm1[0][d], m2=sm2[0][d]; int am=sam[0][d];
    #pragma unroll
    for (int p=1;p<4;++p) poolMerge(m1,m2,am, sm1[p][d], sm2[p][d], sam[p][d]);
    fm1[d]=m1; fm2[d]=m2; fam[d]=am;
  }
  __syncthreads();

  // ---- cat build: catb[8][256] bf16 from hcur + pooled ----
  #pragma unroll
  for (int rep=0; rep<4; ++rep){
    int e = rep*512 + tid;
    int t = e >> 8, c = e & 255;
    int n = (t0 & 255) + t;
    float v;
    if (c < DD) v = hcur[t*128 + c];
    else { int cc = c - DD; v = (n==fam[cc]) ? fm2[cc] : fm1[cc]; }
    catb[t*256 + c] = f2b(v);
  }
  __syncthreads();

  int n0a = wv*16;

  // ---- stage A: [16x128] = cat[16x256] @ Wp; gather f32 B-frags ----
  {
    float wA[8][8];
    #pragma unroll
    for (int ks=0; ks<8; ++ks)
      #pragma unroll
      for (int j=0; j<8; ++j)
        wA[ks][j] = Wp[(size_t)(ks*32 + q*8 + j)*128 + n0a + m];
    SCHED_FENCE();
    f32x4 acc = {0.f,0.f,0.f,0.f};
    const ushort_t* ap = catb + m*256 + q*8;
    #pragma unroll
    for (int ks=0; ks<8; ++ks){
      bf16x8 wf;
      #pragma unroll
      for (int j=0;j<8;++j) wf[j] = (short)f2b(wA[ks][j]);
      bf16x8 af = *(const bf16x8*)(ap + ks*32);
      acc = __builtin_amdgcn_mfma_f32_16x16x32_bf16(af, wf, acc, 0,0,0);
    }
    #pragma unroll
    for (int r=0;r<4;++r) sA[(q*4+r)*128 + n0a + m] = acc[r];
  }
  __syncthreads();

  // ---- LN-A: wave t = token t; lane handles d = 2g, 2g+1 ----
  {
    int t = wv, g = lane;
    float2 v2 = *(const float2*)&sA[t*128 + 2*g];
    float v0 = v2.x + bp[2*g]   + hcur[t*128 + 2*g];
    float v1 = v2.y + bp[2*g+1] + hcur[t*128 + 2*g + 1];
    float s = v0+v1, qq = v0*v0 + v1*v1;
    waveRed2(s,qq);
    float mean = s*(1.f/128), var = qq*(1.f/128) - mean*mean;
    float rs = rsqrtf(var + EPSV);
    float o0 = (v0-mean)*rs*gp[2*g]   + bgp[2*g];
    float o1 = (v1-mean)*rs*gp[2*g+1] + bgp[2*g+1];
    unsigned pk = (unsigned)f2b(o0) | ((unsigned)f2b(o1) << 16);
    *(unsigned*)&h1b[t*128 + 2*g] = pk;
    *(float2*)&h1f[t*128 + 2*g] = make_float2(o0, o1);
  }
  __syncthreads();

  // ---- stage B: [16x512] = h1[16x128] @ W1, two column-tile halves ----
  {
    const ushort_t* ap = h1b + m*128 + q*8;
    bf16x8 af[4];
    #pragma unroll
    for (int ks=0; ks<4; ++ks) af[ks] = *(const bf16x8*)(ap + ks*32);
    #pragma unroll
    for (int half=0; half<2; ++half){
      float wB[8][8];
      #pragma unroll
      for (int i=0;i<2;++i){
        int n0 = (half*2+i)*128 + wv*16;
        #pragma unroll
        for (int ks=0; ks<4; ++ks)
          #pragma unroll
          for (int j=0;j<8;++j)
            wB[i*4+ks][j] = W1[(size_t)(ks*32 + q*8 + j)*512 + n0 + m];
      }
      SCHED_FENCE();
      #pragma unroll
      for (int i=0;i<2;++i){
        int n0 = (half*2+i)*128 + wv*16;
        f32x4 acc = {0.f,0.f,0.f,0.f};
        #pragma unroll
        for (int ks=0; ks<4; ++ks){
          bf16x8 wf;
          #pragma unroll
          for (int j=0;j<8;++j) wf[j] = (short)f2b(wB[i*4+ks][j]);
          acc = __builtin_amdgcn_mfma_f32_16x16x32_bf16(af[ks], wf, acc, 0,0,0);
        }
        float bb = b1[n0+m];
        #pragma unroll
        for (int r=0;r<4;++r)
          ub[(q*4+r)*512 + n0 + m] = f2b(fmaxf(acc[r] + bb, 0.f));
      }
    }
  }
  __syncthreads();

  // ---- stage C: [16x128] = u[16x512] @ W2, two k-halves ----
  {
    f32x4 acc = {0.f,0.f,0.f,0.f};
    const ushort_t* ap = ub + m*512 + q*8;
    #pragma unroll
    for (int half=0; half<2; ++half){
      float wC[8][8];
      #pragma unroll
      for (int ks=0; ks<8; ++ks)
        #pragma unroll
        for (int j=0;j<8;++j)
          wC[ks][j] = W2[(size_t)((half*8+ks)*32 + q*8 + j)*128 + n0a + m];
      SCHED_FENCE();
      #pragma unroll
      for (int ks=0; ks<8; ++ks){
        bf16x8 wf;
        #pragma unroll
        for (int j=0;j<8;++j) wf[j] = (short)f2b(wC[ks][j]);
        bf16x8 af = *(const bf16x8*)(ap + (half*8+ks)*32);
        acc = __builtin_amdgcn_mfma_f32_16x16x32_bf16(af, wf, acc, 0,0,0);
      }
    }
    #pragma unroll
    for (int r=0;r<4;++r) sA[(q*4+r)*128 + n0a + m] = acc[r];
  }
  __syncthreads();

  // ---- LN-C: residual h1f -> hio (+ hcur for pool partial) ----
  {
    int t = wv, g = lane;
    float2 v2 = *(const float2*)&sA[t*128 + 2*g];
    float v0 = v2.x + b2[2*g]   + h1f[t*128 + 2*g];
    float v1 = v2.y + b2[2*g+1] + h1f[t*128 + 2*g + 1];
    float s = v0+v1, qq = v0*v0 + v1*v1;
    waveRed2(s,qq);
    float mean = s*(1.f/128), var = qq*(1.f/128) - mean*mean;
    float rs = rsqrtf(var + EPSV);
    float o0 = (v0-mean)*rs*gf[2*g]   + bgf[2*g];
    float o1 = (v1-mean)*rs*gf[2*g+1] + bgf[2*g+1];
    *(float2*)&hio[(size_t)(t0+t)*DD + 2*g] = make_float2(o0, o1);
    *(float2*)&hcur[t*128 + 2*g] = make_float2(o0, o1);
  }
  if (layer == 0){
    __syncthreads();
    if (tid < 128){
      int n0 = t0 & 255;
      float m1 = hcur[tid], m2 = -3.4e38f; int am = n0;
      #pragma unroll
      for (int p=1;p<TPB;++p)
        poolMerge(m1,m2,am, hcur[p*128+tid], -3.4e38f, n0+p);
      size_t idx = ((size_t)b*BPL + blk)*128 + tid;
      pm1[idx]=m1; pm2[idx]=m2; pma[idx]=am;
    }
  }
}

extern "C" void kernel_launch(void* const* d_in, const int* in_sizes, int n_in,
                              void* d_out, int out_size, void* d_ws, size_t ws_size,
                              hipStream_t stream)
{
  const float* x   = (const float*)d_in[0];
  const float* We  = (const float*)d_in[1];
  const float* be  = (const float*)d_in[2];
  const float* ge  = (const float*)d_in[3];
  const float* bge = (const float*)d_in[4];
  const float* Wp  = (const float*)d_in[5];
  const float* bp  = (const float*)d_in[6];
  const float* gp  = (const float*)d_in[7];
  const float* bgp = (const float*)d_in[8];
  const float* W1  = (const float*)d_in[9];
  const float* b1  = (const float*)d_in[10];
  const float* W2  = (const float*)d_in[11];
  const float* b2  = (const float*)d_in[12];
  const float* gf  = (const float*)d_in[13];
  const float* bgf = (const float*)d_in[14];

  float* hio = (float*)d_out;
  char* ws = (char*)d_ws;
  const size_t NP = (size_t)BB*BPL*128;     // 32768
  float* p1 = (float*)ws;            ws += NP*4;
  float* p2 = (float*)ws;            ws += NP*4;
  int*   pa = (int*)ws;              ws += NP*4;

  const int grid = (BB*NN)/TPB;   // 256

  k_net<<<grid, 512, 0, stream>>>(0, x, We, be, ge, bge, hio, p1, p2, pa,
      Wp,                    bp,      gp,      bgp,
      W1,                    b1,      W2,      b2,
      gf,                    bgf);

  k_net<<<grid, 512, 0, stream>>>(1, x, We, be, ge, bge, hio, p1, p2, pa,
      Wp + (size_t)2*DD*DD,  bp + DD, gp + DD, bgp + DD,
      W1 + (size_t)DD*HH,    b1 + HH, W2 + (size_t)HH*DD, b2 + DD,
      gf + DD,               bgf + DD);
}